// Round 6
// baseline (3646.970 us; speedup 1.0000x reference)
//
#include <hip/hip_runtime.h>
#include <hip/hip_fp16.h>

#define N_LINKS 262144
#define N_PAIRS 4194304
#define F 20
#define XS 32                   // padded X1h row stride in halfs (64 B)
#define T_ITERS 4
#define NBUCK 4096              // buckets of 64 links: bucket = second >> 6
#define LPB 64                  // links per bucket
#define BCAP 2048               // max pairs staged per bucket (mean 1024)
#define NSEG (NBUCK * 16)       // (bucket,grp,q) segments: 4 grps x 4 quarters

__device__ __forceinline__ float selu_f(float x) {
    const float scale = 1.0507009873554805f;
    const float scale_alpha = 1.7580993408473766f;  // scale * alpha
    return x > 0.0f ? scale * x : scale_alpha * (__expf(x) - 1.0f);
}

__device__ __forceinline__ float sigmoid_f(float x) {
    return 1.0f / (1.0f + __expf(-x));
}

__device__ __forceinline__ float tanh_fast(float x) {
    x = fminf(fmaxf(x, -15.0f), 15.0f);
    float e = __expf(2.0f * x);
    return (e - 1.0f) / (e + 1.0f);
}

// ---------------- CSR build (once per call; graph is static) ----------------

__global__ void k_hist(const int* __restrict__ second, int* __restrict__ bhist) {
    __shared__ int h[NBUCK];
    for (int i = threadIdx.x; i < NBUCK; i += blockDim.x) h[i] = 0;
    __syncthreads();
    for (int p = blockIdx.x * blockDim.x + threadIdx.x; p < N_PAIRS;
         p += gridDim.x * blockDim.x)
        atomicAdd(&h[second[p] >> 6], 1);
    __syncthreads();
    for (int i = threadIdx.x; i < NBUCK; i += blockDim.x) {
        int c = h[i];
        if (c) atomicAdd(&bhist[i], c);
    }
}

__global__ void k_scan(const int* __restrict__ bhist,
                       int* __restrict__ bstart, int* __restrict__ bcursor,
                       int* __restrict__ rsg) {
    __shared__ int sums[1024];
    const int tid = threadIdx.x;
    const int b0 = tid * 4;
    int local[4];
    int s = 0;
#pragma unroll
    for (int i = 0; i < 4; ++i) { local[i] = bhist[b0 + i]; s += local[i]; }
    sums[tid] = s;
    __syncthreads();
    for (int off = 1; off < 1024; off <<= 1) {
        int v = (tid >= off) ? sums[tid - off] : 0;
        __syncthreads();
        sums[tid] += v;
        __syncthreads();
    }
    int run = (tid == 0) ? 0 : sums[tid - 1];
#pragma unroll
    for (int i = 0; i < 4; ++i) {
        bstart[b0 + i] = run;
        bcursor[b0 + i] = run;
        run += local[i];
    }
    if (tid == 1023) { bstart[NBUCK] = run; rsg[NSEG] = run; }
}

// Per-block reservation partition into buckets; entry = {first:18 | dst&63:6}.
#define FILL_BLOCKS 128
#define FILL_THREADS 1024
__global__ void __launch_bounds__(FILL_THREADS)
k_fill(const int* __restrict__ first, const int* __restrict__ second,
       int* __restrict__ bcursor, unsigned* __restrict__ sortedA) {
    __shared__ int h[NBUCK];
    __shared__ int resv[NBUCK];
    const int chunk = N_PAIRS / FILL_BLOCKS;   // 32768
    const int base = blockIdx.x * chunk;
    for (int i = threadIdx.x; i < NBUCK; i += blockDim.x) h[i] = 0;
    __syncthreads();
    for (int i = threadIdx.x; i < chunk; i += blockDim.x)
        atomicAdd(&h[second[base + i] >> 6], 1);
    __syncthreads();
    for (int i = threadIdx.x; i < NBUCK; i += blockDim.x) {
        int c = h[i];
        resv[i] = c ? atomicAdd(&bcursor[i], c) : 0;
        h[i] = 0;  // reuse as local cursor
    }
    __syncthreads();
    for (int i = threadIdx.x; i < chunk; i += blockDim.x) {
        int s = second[base + i];
        int b = s >> 6;
        int pos = resv[b] + atomicAdd(&h[b], 1);
        sortedA[pos] = (unsigned)first[base + i] | ((unsigned)(s & 63) << 18);
    }
}

// One block per bucket: in-LDS counting sort by key (grp:2 | quarter:2).
// Output entries: {src:18 | li:4} (li = link-within-16-link-group).
// rsg[bucket*16 + grp*4 + q] = global start of each segment.
__global__ void __launch_bounds__(256)
k_refine(const int* __restrict__ bstart, const unsigned* __restrict__ sortedA,
         int* __restrict__ ent_out, int* __restrict__ rsg) {
    __shared__ unsigned ent[BCAP];
    __shared__ int outv[BCAP];
    __shared__ int cnt[16];
    __shared__ int off[16];
    const int b = blockIdx.x;
    const int s = bstart[b];
    int n = bstart[b + 1] - s;
    if (n > BCAP) n = BCAP;  // statistically impossible (mean 1024, 30+ sigma)
    for (int i = threadIdx.x; i < n; i += 256) ent[i] = sortedA[s + i];
    if (threadIdx.x < 16) cnt[threadIdx.x] = 0;
    __syncthreads();
    for (int i = threadIdx.x; i < n; i += 256) {
        unsigned v = ent[i];
        int key = (int)(((v >> 22) & 3) * 4 + ((v & 0x3FFFF) >> 16));
        atomicAdd(&cnt[key], 1);
    }
    __syncthreads();
    if (threadIdx.x < 16) {
        int acc = 0;
        for (int j = 0; j < threadIdx.x; ++j) acc += cnt[j];
        off[threadIdx.x] = acc;
        rsg[b * 16 + threadIdx.x] = s + acc;
    }
    __syncthreads();
    for (int i = threadIdx.x; i < n; i += 256) {
        unsigned v = ent[i];
        int key = (int)(((v >> 22) & 3) * 4 + ((v & 0x3FFFF) >> 16));
        int pos = atomicAdd(&off[key], 1);
        outv[pos] = (int)((v & 0x3FFFF) | (((v >> 18) & 15) << 18));
    }
    __syncthreads();
    for (int i = threadIdx.x; i < n; i += 256) ent_out[s + i] = outv[i];
}

// ---------------- per-iteration kernels ----------------

// X1h[l] = fp16(W1 @ state[l] + b_msg), padded 64B rows ; X2[l] = W2 @ state[l]
__global__ void k_premsg(const float* __restrict__ state,
                         const float* __restrict__ W_msg,
                         const float* __restrict__ b_msg,
                         __half* __restrict__ X1h, float* __restrict__ X2) {
    __shared__ float Wl[F * 2 * F];
    __shared__ float bl[F];
    for (int i = threadIdx.x; i < F * 2 * F; i += blockDim.x) Wl[i] = W_msg[i];
    if (threadIdx.x < F) bl[threadIdx.x] = b_msg[threadIdx.x];
    __syncthreads();

    int l = blockIdx.x * blockDim.x + threadIdx.x;

    float s[F];
    const float4* sp = (const float4*)(state + (size_t)l * F);
#pragma unroll
    for (int i = 0; i < 5; ++i) {
        float4 v = sp[i];
        s[4*i+0] = v.x; s[4*i+1] = v.y; s[4*i+2] = v.z; s[4*i+3] = v.w;
    }
    float o1[F], o2[F];
#pragma unroll
    for (int o = 0; o < F; ++o) {
        float a1 = bl[o], a2 = 0.0f;
#pragma unroll
        for (int k = 0; k < F; ++k) {
            a1 = fmaf(Wl[o * 2 * F + k],     s[k], a1);
            a2 = fmaf(Wl[o * 2 * F + F + k], s[k], a2);
        }
        o1[o] = a1; o2[o] = a2;
    }
    __half2* xp = (__half2*)(X1h + (size_t)l * XS);
#pragma unroll
    for (int i = 0; i < 10; ++i)
        xp[i] = __halves2half2(__float2half(o1[2*i]), __float2half(o1[2*i+1]));
    const __half2 z2 = __halves2half2(__float2half(0.f), __float2half(0.f));
#pragma unroll
    for (int i = 10; i < 16; ++i) xp[i] = z2;   // zero the pad region
    float4* x2p = (float4*)(X2 + (size_t)l * F);
#pragma unroll
    for (int i = 0; i < 5; ++i)
        x2p[i] = make_float4(o2[4*i], o2[4*i+1], o2[4*i+2], o2[4*i+3]);
}

// Block = one 64-link bucket. Wave w owns links [w*16, w*16+16) via a private
// LDS accumulator slice; X2 staged in LDS once. Each wave walks its pairs in
// source-quarter order (q=0..3), so the chip-wide live gather set per phase is
// ~4.2 MB (L2-resident). Inner loop: 2 pairs/round, entries preloaded 64 at a
// time and broadcast by shuffle; ds atomics have <=2-way conflicts (free).
__global__ void __launch_bounds__(256)
k_agg(const int* __restrict__ rsg, const int* __restrict__ ents,
      const __half* __restrict__ X1h, const float* __restrict__ X2,
      float* __restrict__ agg) {
    __shared__ float x2L[LPB * F];      // 5 KB
    __shared__ float accL[LPB * F];     // 5 KB
    const int b = blockIdx.x;
    for (int i = threadIdx.x; i < LPB * F; i += 256) {
        x2L[i] = X2[(size_t)b * LPB * F + i];
        accL[i] = 0.0f;
    }
    __syncthreads();
    const int wave = threadIdx.x >> 6;          // = grp (16-link group)
    const int lane = threadIdx.x & 63;
    const int f = lane & 31;
    const int half = lane >> 5;
    const int fidx = (f < F) ? f : (F - 1);     // safe slot for pad lanes
    float* accW = accL + wave * 16 * F;
    const float* x2W = x2L + wave * 16 * F;
    const int segbase = b * 16 + wave * 4;

    for (int q = 0; q < 4; ++q) {
        const int S = rsg[segbase + q];
        const int E = rsg[segbase + q + 1];     // contiguous across q/grp/bucket
        for (int base = S; base < E; base += 64) {
            const int nc = min(64, E - base);
            const int e_reg = ents[base + min(lane, nc - 1)];
            const int rounds = (nc + 1) >> 1;
#pragma unroll 4
            for (int r = 0; r < rounds; ++r) {
                const int i = (r << 1) + half;
                const int idx = min(i, nc - 1);
                const int e = __shfl(e_reg, idx, 64);
                const int src = e & 0x3FFFF;
                const int li = e >> 18;         // 0..15
                const float x1 = __half2float(X1h[((size_t)src << 5) + f]);
                float x = x1 + x2W[li * F + fidx];
                x = (i < nc && f < F) ? x : 0.0f;   // selu(0)=0 -> no-op add
                atomicAdd(&accW[li * F + fidx], selu_f(x));
            }
        }
    }
    __syncthreads();
    for (int i = threadIdx.x; i < LPB * F; i += 256)
        agg[(size_t)b * LPB * F + i] = accL[i];
}

// GRU fused with next-iteration premsg (flags&1) and feature reduce (flags&2).
__global__ void __launch_bounds__(256)
k_gru(const float* __restrict__ agg, const float* __restrict__ h_in,
      const float* __restrict__ W_ih, const float* __restrict__ W_hh,
      const float* __restrict__ b_ih, const float* __restrict__ b_hh,
      const float* __restrict__ W_msg, const float* __restrict__ b_msg,
      float* __restrict__ h_out, __half* __restrict__ X1h, float* __restrict__ X2,
      float* __restrict__ feature, int flags) {
    __shared__ float Wi[3 * F * F];
    __shared__ float Wh[3 * F * F];
    __shared__ float Wm[F * 2 * F];
    __shared__ float bi[3 * F];
    __shared__ float bh[3 * F];
    __shared__ float bm[F];
    __shared__ float red[4 * F];
    for (int i = threadIdx.x; i < 3 * F * F; i += blockDim.x) {
        Wi[i] = W_ih[i];
        Wh[i] = W_hh[i];
    }
    for (int i = threadIdx.x; i < F * 2 * F; i += blockDim.x) Wm[i] = W_msg[i];
    if (threadIdx.x < 3 * F) {
        bi[threadIdx.x] = b_ih[threadIdx.x];
        bh[threadIdx.x] = b_hh[threadIdx.x];
    }
    if (threadIdx.x < F) bm[threadIdx.x] = b_msg[threadIdx.x];
    __syncthreads();

    const int l = blockIdx.x * blockDim.x + threadIdx.x;

    float m[F], h[F];
    const float4* mp = (const float4*)(agg  + (size_t)l * F);
    const float4* hp = (const float4*)(h_in + (size_t)l * F);
#pragma unroll
    for (int i = 0; i < 5; ++i) {
        float4 vm = mp[i], vh = hp[i];
        m[4*i+0] = vm.x; m[4*i+1] = vm.y; m[4*i+2] = vm.z; m[4*i+3] = vm.w;
        h[4*i+0] = vh.x; h[4*i+1] = vh.y; h[4*i+2] = vh.z; h[4*i+3] = vh.w;
    }

    float hn[F];
#pragma unroll
    for (int j = 0; j < F; ++j) {
        float gr = bi[j]     + bh[j];
        float gz = bi[F + j] + bh[F + j];
        float gi_n = bi[2*F + j];
        float gh_n = bh[2*F + j];
        float gr_i = 0.f, gz_i = 0.f, gr_h = 0.f, gz_h = 0.f;
#pragma unroll
        for (int k = 0; k < F; ++k) {
            gr_i = fmaf(Wi[(0*F + j) * F + k], m[k], gr_i);
            gz_i = fmaf(Wi[(1*F + j) * F + k], m[k], gz_i);
            gi_n = fmaf(Wi[(2*F + j) * F + k], m[k], gi_n);
            gr_h = fmaf(Wh[(0*F + j) * F + k], h[k], gr_h);
            gz_h = fmaf(Wh[(1*F + j) * F + k], h[k], gz_h);
            gh_n = fmaf(Wh[(2*F + j) * F + k], h[k], gh_n);
        }
        float r = sigmoid_f(gr + gr_i + gr_h);
        float z = sigmoid_f(gz + gz_i + gz_h);
        float n = tanh_fast(gi_n + r * gh_n);
        hn[j] = (1.0f - z) * n + z * h[j];
    }

    float4* op = (float4*)(h_out + (size_t)l * F);
#pragma unroll
    for (int i = 0; i < 5; ++i)
        op[i] = make_float4(hn[4*i], hn[4*i+1], hn[4*i+2], hn[4*i+3]);

    if (flags & 1) {  // premsg for next iteration from hn
        float o1[F], o2[F];
#pragma unroll
        for (int o = 0; o < F; ++o) {
            float a1 = bm[o], a2 = 0.0f;
#pragma unroll
            for (int k = 0; k < F; ++k) {
                a1 = fmaf(Wm[o * 2 * F + k],     hn[k], a1);
                a2 = fmaf(Wm[o * 2 * F + F + k], hn[k], a2);
            }
            o1[o] = a1; o2[o] = a2;
        }
        __half2* xp = (__half2*)(X1h + (size_t)l * XS);
#pragma unroll
        for (int i = 0; i < 10; ++i)
            xp[i] = __halves2half2(__float2half(o1[2*i]), __float2half(o1[2*i+1]));
        float4* x2p = (float4*)(X2 + (size_t)l * F);
#pragma unroll
        for (int i = 0; i < 5; ++i)
            x2p[i] = make_float4(o2[4*i], o2[4*i+1], o2[4*i+2], o2[4*i+3]);
    }

    if (flags & 2) {  // feature reduction: sum hn over all links
#pragma unroll
        for (int off = 1; off < 64; off <<= 1) {
#pragma unroll
            for (int j = 0; j < F; ++j) hn[j] += __shfl_xor(hn[j], off, 64);
        }
        const int lane = threadIdx.x & 63;
        const int wave = threadIdx.x >> 6;
        if (lane == 0) {
#pragma unroll
            for (int j = 0; j < F; ++j) red[wave * F + j] = hn[j];
        }
        __syncthreads();
        if (threadIdx.x < F) {
            float s = red[threadIdx.x] + red[F + threadIdx.x] +
                      red[2 * F + threadIdx.x] + red[3 * F + threadIdx.x];
            atomicAdd(&feature[threadIdx.x], s);
        }
    }
}

__global__ void k_readout(const float* __restrict__ feature,
                          const float* __restrict__ W_r1, const float* __restrict__ b_r1,
                          const float* __restrict__ W_r2, const float* __restrict__ b_r2,
                          const float* __restrict__ W_out, const float* __restrict__ b_out,
                          float* __restrict__ out) {
    if (threadIdx.x != 0 || blockIdx.x != 0) return;
    float fv[F], h1[F], h2[F];
#pragma unroll
    for (int i = 0; i < F; ++i) fv[i] = feature[i];
#pragma unroll
    for (int o = 0; o < F; ++o) {
        float a = b_r1[o];
#pragma unroll
        for (int k = 0; k < F; ++k) a = fmaf(W_r1[o * F + k], fv[k], a);
        h1[o] = selu_f(a);
    }
#pragma unroll
    for (int o = 0; o < F; ++o) {
        float a = b_r2[o];
#pragma unroll
        for (int k = 0; k < F; ++k) a = fmaf(W_r2[o * F + k], h1[k], a);
        h2[o] = selu_f(a);
    }
    float a = b_out[0];
#pragma unroll
    for (int k = 0; k < F; ++k) a = fmaf(W_out[k], h2[k], a);
    out[0] = a;
}

extern "C" void kernel_launch(void* const* d_in, const int* in_sizes, int n_in,
                              void* d_out, int out_size, void* d_ws, size_t ws_size,
                              hipStream_t stream) {
    const float* link_state = (const float*)d_in[0];
    const int*   first      = (const int*)  d_in[1];
    const int*   second     = (const int*)  d_in[2];
    // d_in[3] = state_dim (unused)
    const float* W_msg = (const float*)d_in[4];
    const float* b_msg = (const float*)d_in[5];
    const float* W_ih  = (const float*)d_in[6];
    const float* W_hh  = (const float*)d_in[7];
    const float* b_ih  = (const float*)d_in[8];
    const float* b_hh  = (const float*)d_in[9];
    const float* W_r1  = (const float*)d_in[10];
    const float* b_r1  = (const float*)d_in[11];
    const float* W_r2  = (const float*)d_in[12];
    const float* b_r2  = (const float*)d_in[13];
    const float* W_out = (const float*)d_in[14];
    const float* b_out = (const float*)d_in[15];
    float* out = (float*)d_out;

    const size_t NF = (size_t)N_LINKS * F;
    float* state   = (float*)d_ws;                    // 21 MB
    float* X2      = state + NF;                      // 21 MB
    float* agg     = X2 + NF;                         // 21 MB (aliases sortedA)
    __half* X1h    = (__half*)(agg + NF);             // 16.8 MB (64B rows)
    int*    ents   = (int*)(X1h + (size_t)N_LINKS * XS);  // 16.8 MB
    int*    rsg    = ents + N_PAIRS;                  // 256 KB (+1)
    float* feature = (float*)(rsg + NSEG + 1);        // 128 B slot
    int* bhist     = (int*)(feature + 32);
    int* bstart    = bhist + NBUCK;                   // NBUCK+1
    int* bcursor   = bstart + NBUCK + 1;
    unsigned* sortedA = (unsigned*)agg;               // lifetime: fill..refine only

    hipMemsetAsync(bhist, 0, NBUCK * sizeof(int), stream);
    hipMemsetAsync(feature, 0, F * sizeof(float), stream);

    k_hist<<<128, 512, 0, stream>>>(second, bhist);
    k_scan<<<1, 1024, 0, stream>>>(bhist, bstart, bcursor, rsg);
    k_fill<<<FILL_BLOCKS, FILL_THREADS, 0, stream>>>(first, second, bcursor, sortedA);
    k_refine<<<NBUCK, 256, 0, stream>>>(bstart, sortedA, ents, rsg);

    k_premsg<<<N_LINKS / 256, 256, 0, stream>>>(link_state, W_msg, b_msg, X1h, X2);
    for (int t = 0; t < T_ITERS; ++t) {
        const float* h = (t == 0) ? link_state : state;
        int flags = (t < T_ITERS - 1 ? 1 : 0) | (t == T_ITERS - 1 ? 2 : 0);
        k_agg<<<NBUCK, 256, 0, stream>>>(rsg, ents, X1h, X2, agg);
        k_gru<<<N_LINKS / 256, 256, 0, stream>>>(agg, h, W_ih, W_hh, b_ih, b_hh,
                                                 W_msg, b_msg, state, X1h, X2,
                                                 feature, flags);
    }
    k_readout<<<1, 64, 0, stream>>>(feature, W_r1, b_r1, W_r2, b_r2, W_out, b_out, out);
}

// Round 7
// 1007.296 us; speedup vs baseline: 3.6206x; 3.6206x over previous
//
#include <hip/hip_runtime.h>
#include <hip/hip_fp16.h>

#define N_LINKS 262144
#define N_PAIRS 4194304
#define F 20
#define XB 32                   // X1 fp8 row stride in BYTES (32 B, half a line)
#define T_ITERS 4
#define NBUCK 4096              // buckets of 64 links: bucket = second >> 6
#define LPB 64                  // links per bucket
#define BCAP 2048               // max pairs staged per bucket (mean 1024)

__device__ __forceinline__ float selu_f(float x) {
    const float scale = 1.0507009873554805f;
    const float scale_alpha = 1.7580993408473766f;  // scale * alpha
    return x > 0.0f ? scale * x : scale_alpha * (__expf(x) - 1.0f);
}

__device__ __forceinline__ float sigmoid_f(float x) {
    return 1.0f / (1.0f + __expf(-x));
}

__device__ __forceinline__ float tanh_fast(float x) {
    x = fminf(fmaxf(x, -15.0f), 15.0f);
    float e = __expf(2.0f * x);
    return (e - 1.0f) / (e + 1.0f);
}

// Pack 20 floats -> 20 fp8 e4m3 bytes + 12 zero pad, one 32B row (2x int4).
__device__ __forceinline__ void store_row_fp8(unsigned char* rowp, const float* o1) {
    int d[8];
#pragma unroll
    for (int i = 0; i < 5; ++i) {
        int w = 0;
        w = __builtin_amdgcn_cvt_pk_fp8_f32(o1[4*i+0], o1[4*i+1], w, false);
        w = __builtin_amdgcn_cvt_pk_fp8_f32(o1[4*i+2], o1[4*i+3], w, true);
        d[i] = w;
    }
    d[5] = d[6] = d[7] = 0;
    ((int4*)rowp)[0] = make_int4(d[0], d[1], d[2], d[3]);
    ((int4*)rowp)[1] = make_int4(d[4], d[5], d[6], d[7]);
}

// ---------------- CSR build (once per call; graph is static) ----------------

__global__ void k_hist(const int* __restrict__ second, int* __restrict__ bhist) {
    __shared__ int h[NBUCK];
    for (int i = threadIdx.x; i < NBUCK; i += blockDim.x) h[i] = 0;
    __syncthreads();
    for (int p = blockIdx.x * blockDim.x + threadIdx.x; p < N_PAIRS;
         p += gridDim.x * blockDim.x)
        atomicAdd(&h[second[p] >> 6], 1);
    __syncthreads();
    for (int i = threadIdx.x; i < NBUCK; i += blockDim.x) {
        int c = h[i];
        if (c) atomicAdd(&bhist[i], c);
    }
}

__global__ void k_scan(const int* __restrict__ bhist,
                       int* __restrict__ bstart, int* __restrict__ bcursor,
                       int* __restrict__ rs) {
    __shared__ int sums[1024];
    const int tid = threadIdx.x;
    const int b0 = tid * 4;
    int local[4];
    int s = 0;
#pragma unroll
    for (int i = 0; i < 4; ++i) { local[i] = bhist[b0 + i]; s += local[i]; }
    sums[tid] = s;
    __syncthreads();
    for (int off = 1; off < 1024; off <<= 1) {
        int v = (tid >= off) ? sums[tid - off] : 0;
        __syncthreads();
        sums[tid] += v;
        __syncthreads();
    }
    int run = (tid == 0) ? 0 : sums[tid - 1];
#pragma unroll
    for (int i = 0; i < 4; ++i) {
        bstart[b0 + i] = run;
        bcursor[b0 + i] = run;
        run += local[i];
    }
    if (tid == 1023) { bstart[NBUCK] = run; rs[N_LINKS] = run; }
}

// Per-block reservation partition into buckets; entry = {first:18 | dst&63:6}.
#define FILL_BLOCKS 128
#define FILL_THREADS 1024
__global__ void __launch_bounds__(FILL_THREADS)
k_fill(const int* __restrict__ first, const int* __restrict__ second,
       int* __restrict__ bcursor, unsigned* __restrict__ sortedA) {
    __shared__ int h[NBUCK];
    __shared__ int resv[NBUCK];
    const int chunk = N_PAIRS / FILL_BLOCKS;   // 32768
    const int base = blockIdx.x * chunk;
    for (int i = threadIdx.x; i < NBUCK; i += blockDim.x) h[i] = 0;
    __syncthreads();
    for (int i = threadIdx.x; i < chunk; i += blockDim.x)
        atomicAdd(&h[second[base + i] >> 6], 1);
    __syncthreads();
    for (int i = threadIdx.x; i < NBUCK; i += blockDim.x) {
        int c = h[i];
        resv[i] = c ? atomicAdd(&bcursor[i], c) : 0;
        h[i] = 0;  // reuse as local cursor
    }
    __syncthreads();
    for (int i = threadIdx.x; i < chunk; i += blockDim.x) {
        int s = second[base + i];
        int b = s >> 6;
        int pos = resv[b] + atomicAdd(&h[b], 1);
        sortedA[pos] = (unsigned)first[base + i] | ((unsigned)(s & 63) << 18);
    }
}

// One block per bucket: in-LDS counting sort -> per-link CSR (rs + srcs).
__global__ void __launch_bounds__(256)
k_refine(const int* __restrict__ bstart, const unsigned* __restrict__ sortedA,
         int* __restrict__ srcs, int* __restrict__ rs) {
    __shared__ unsigned ent[BCAP];
    __shared__ int outv[BCAP];
    __shared__ int cnt[LPB];
    __shared__ int off[LPB];
    const int b = blockIdx.x;
    const int s = bstart[b];
    int n = bstart[b + 1] - s;
    if (n > BCAP) n = BCAP;  // statistically impossible (mean 1024, 30+ sigma)
    for (int i = threadIdx.x; i < n; i += 256) ent[i] = sortedA[s + i];
    if (threadIdx.x < LPB) cnt[threadIdx.x] = 0;
    __syncthreads();
    for (int i = threadIdx.x; i < n; i += 256)
        atomicAdd(&cnt[ent[i] >> 18], 1);
    __syncthreads();
    if (threadIdx.x < LPB) {
        int acc = 0;
        for (int j = 0; j < threadIdx.x; ++j) acc += cnt[j];
        off[threadIdx.x] = acc;
        rs[b * LPB + threadIdx.x] = s + acc;
    }
    __syncthreads();
    for (int i = threadIdx.x; i < n; i += 256) {
        unsigned v = ent[i];
        int pos = atomicAdd(&off[v >> 18], 1);
        outv[pos] = (int)(v & 0x3FFFF);
    }
    __syncthreads();
    for (int i = threadIdx.x; i < n; i += 256) srcs[s + i] = outv[i];
}

// ---------------- per-iteration kernels ----------------

// X1b[l] = fp8(W1 @ state[l] + b_msg), 32B rows ; X2[l] = W2 @ state[l]
__global__ void k_premsg(const float* __restrict__ state,
                         const float* __restrict__ W_msg,
                         const float* __restrict__ b_msg,
                         unsigned char* __restrict__ X1b, float* __restrict__ X2) {
    __shared__ float Wl[F * 2 * F];
    __shared__ float bl[F];
    for (int i = threadIdx.x; i < F * 2 * F; i += blockDim.x) Wl[i] = W_msg[i];
    if (threadIdx.x < F) bl[threadIdx.x] = b_msg[threadIdx.x];
    __syncthreads();

    int l = blockIdx.x * blockDim.x + threadIdx.x;

    float s[F];
    const float4* sp = (const float4*)(state + (size_t)l * F);
#pragma unroll
    for (int i = 0; i < 5; ++i) {
        float4 v = sp[i];
        s[4*i+0] = v.x; s[4*i+1] = v.y; s[4*i+2] = v.z; s[4*i+3] = v.w;
    }
    float o1[F], o2[F];
#pragma unroll
    for (int o = 0; o < F; ++o) {
        float a1 = bl[o], a2 = 0.0f;
#pragma unroll
        for (int k = 0; k < F; ++k) {
            a1 = fmaf(Wl[o * 2 * F + k],     s[k], a1);
            a2 = fmaf(Wl[o * 2 * F + F + k], s[k], a2);
        }
        o1[o] = a1; o2[o] = a2;
    }
    store_row_fp8(X1b + (size_t)l * XB, o1);
    float4* x2p = (float4*)(X2 + (size_t)l * F);
#pragma unroll
    for (int i = 0; i < 5; ++i)
        x2p[i] = make_float4(o2[4*i], o2[4*i+1], o2[4*i+2], o2[4*i+3]);
}

// Wave-per-link gather-aggregate, high-MLP layout:
// lane l: f = l&31 (feature byte, valid f<20), half = l>>5 (pair of the round).
// Round r covers pairs 2r, 2r+1 -> each pair = one 32B fp8 row (one 64B line);
// rounds independent (srcs preloaded into a register, broadcast via shuffles).
__global__ void __launch_bounds__(256)
k_agg(const int* __restrict__ rs, const int* __restrict__ srcs,
      const unsigned char* __restrict__ X1b, const float* __restrict__ X2,
      float* __restrict__ agg) {
    const int wave = threadIdx.x >> 6;
    const int l = blockIdx.x * 4 + wave;
    const int lane = threadIdx.x & 63;
    const int f = lane & 31;
    const int half = lane >> 5;

    const float x2f = X2[(size_t)l * F + (f < F ? f : F - 1)];
    const int row_start = rs[l];
    const int cnt = rs[l + 1] - row_start;

    float acc = 0.0f;
    for (int base = 0; base < cnt; base += 64) {
        const int nc = min(64, cnt - base);
        // coalesced preload of up to 64 src indices (clamped duplicate tail)
        const int s_reg = srcs[row_start + base + min(lane, nc - 1)];
        const int rounds = (nc + 1) >> 1;
#pragma unroll 4
        for (int r = 0; r < rounds; ++r) {
            const int i = (r << 1) + half;
            const int idx = min(i, nc - 1);
            const int src = __shfl(s_reg, idx, 64);
            const unsigned b8 = X1b[((size_t)src << 5) + f];
            const float x1 = __builtin_amdgcn_cvt_f32_fp8((int)b8, 0);
            const float v = selu_f(x1 + x2f);
            acc += (i < nc) ? v : 0.0f;
        }
    }
    // lanes l and l^32 hold the same feature f
    acc += __shfl(acc, lane ^ 32, 64);
    if (lane < F) agg[(size_t)l * F + lane] = acc;
}

// GRU fused with next-iteration premsg (flags&1) and feature reduce (flags&2).
__global__ void __launch_bounds__(256)
k_gru(const float* __restrict__ agg, const float* __restrict__ h_in,
      const float* __restrict__ W_ih, const float* __restrict__ W_hh,
      const float* __restrict__ b_ih, const float* __restrict__ b_hh,
      const float* __restrict__ W_msg, const float* __restrict__ b_msg,
      float* __restrict__ h_out, unsigned char* __restrict__ X1b,
      float* __restrict__ X2, float* __restrict__ feature, int flags) {
    __shared__ float Wi[3 * F * F];
    __shared__ float Wh[3 * F * F];
    __shared__ float Wm[F * 2 * F];
    __shared__ float bi[3 * F];
    __shared__ float bh[3 * F];
    __shared__ float bm[F];
    __shared__ float red[4 * F];
    for (int i = threadIdx.x; i < 3 * F * F; i += blockDim.x) {
        Wi[i] = W_ih[i];
        Wh[i] = W_hh[i];
    }
    for (int i = threadIdx.x; i < F * 2 * F; i += blockDim.x) Wm[i] = W_msg[i];
    if (threadIdx.x < 3 * F) {
        bi[threadIdx.x] = b_ih[threadIdx.x];
        bh[threadIdx.x] = b_hh[threadIdx.x];
    }
    if (threadIdx.x < F) bm[threadIdx.x] = b_msg[threadIdx.x];
    __syncthreads();

    const int l = blockIdx.x * blockDim.x + threadIdx.x;

    float m[F], h[F];
    const float4* mp = (const float4*)(agg  + (size_t)l * F);
    const float4* hp = (const float4*)(h_in + (size_t)l * F);
#pragma unroll
    for (int i = 0; i < 5; ++i) {
        float4 vm = mp[i], vh = hp[i];
        m[4*i+0] = vm.x; m[4*i+1] = vm.y; m[4*i+2] = vm.z; m[4*i+3] = vm.w;
        h[4*i+0] = vh.x; h[4*i+1] = vh.y; h[4*i+2] = vh.z; h[4*i+3] = vh.w;
    }

    float hn[F];
#pragma unroll
    for (int j = 0; j < F; ++j) {
        float gr = bi[j]     + bh[j];
        float gz = bi[F + j] + bh[F + j];
        float gi_n = bi[2*F + j];
        float gh_n = bh[2*F + j];
        float gr_i = 0.f, gz_i = 0.f, gr_h = 0.f, gz_h = 0.f;
#pragma unroll
        for (int k = 0; k < F; ++k) {
            gr_i = fmaf(Wi[(0*F + j) * F + k], m[k], gr_i);
            gz_i = fmaf(Wi[(1*F + j) * F + k], m[k], gz_i);
            gi_n = fmaf(Wi[(2*F + j) * F + k], m[k], gi_n);
            gr_h = fmaf(Wh[(0*F + j) * F + k], h[k], gr_h);
            gz_h = fmaf(Wh[(1*F + j) * F + k], h[k], gz_h);
            gh_n = fmaf(Wh[(2*F + j) * F + k], h[k], gh_n);
        }
        float r = sigmoid_f(gr + gr_i + gr_h);
        float z = sigmoid_f(gz + gz_i + gz_h);
        float n = tanh_fast(gi_n + r * gh_n);
        hn[j] = (1.0f - z) * n + z * h[j];
    }

    float4* op = (float4*)(h_out + (size_t)l * F);
#pragma unroll
    for (int i = 0; i < 5; ++i)
        op[i] = make_float4(hn[4*i], hn[4*i+1], hn[4*i+2], hn[4*i+3]);

    if (flags & 1) {  // premsg for next iteration from hn
        float o1[F], o2[F];
#pragma unroll
        for (int o = 0; o < F; ++o) {
            float a1 = bm[o], a2 = 0.0f;
#pragma unroll
            for (int k = 0; k < F; ++k) {
                a1 = fmaf(Wm[o * 2 * F + k],     hn[k], a1);
                a2 = fmaf(Wm[o * 2 * F + F + k], hn[k], a2);
            }
            o1[o] = a1; o2[o] = a2;
        }
        store_row_fp8(X1b + (size_t)l * XB, o1);
        float4* x2p = (float4*)(X2 + (size_t)l * F);
#pragma unroll
        for (int i = 0; i < 5; ++i)
            x2p[i] = make_float4(o2[4*i], o2[4*i+1], o2[4*i+2], o2[4*i+3]);
    }

    if (flags & 2) {  // feature reduction: sum hn over all links
#pragma unroll
        for (int off = 1; off < 64; off <<= 1) {
#pragma unroll
            for (int j = 0; j < F; ++j) hn[j] += __shfl_xor(hn[j], off, 64);
        }
        const int lane = threadIdx.x & 63;
        const int wave = threadIdx.x >> 6;
        if (lane == 0) {
#pragma unroll
            for (int j = 0; j < F; ++j) red[wave * F + j] = hn[j];
        }
        __syncthreads();
        if (threadIdx.x < F) {
            float s = red[threadIdx.x] + red[F + threadIdx.x] +
                      red[2 * F + threadIdx.x] + red[3 * F + threadIdx.x];
            atomicAdd(&feature[threadIdx.x], s);
        }
    }
}

__global__ void k_readout(const float* __restrict__ feature,
                          const float* __restrict__ W_r1, const float* __restrict__ b_r1,
                          const float* __restrict__ W_r2, const float* __restrict__ b_r2,
                          const float* __restrict__ W_out, const float* __restrict__ b_out,
                          float* __restrict__ out) {
    if (threadIdx.x != 0 || blockIdx.x != 0) return;
    float fv[F], h1[F], h2[F];
#pragma unroll
    for (int i = 0; i < F; ++i) fv[i] = feature[i];
#pragma unroll
    for (int o = 0; o < F; ++o) {
        float a = b_r1[o];
#pragma unroll
        for (int k = 0; k < F; ++k) a = fmaf(W_r1[o * F + k], fv[k], a);
        h1[o] = selu_f(a);
    }
#pragma unroll
    for (int o = 0; o < F; ++o) {
        float a = b_r2[o];
#pragma unroll
        for (int k = 0; k < F; ++k) a = fmaf(W_r2[o * F + k], h1[k], a);
        h2[o] = selu_f(a);
    }
    float a = b_out[0];
#pragma unroll
    for (int k = 0; k < F; ++k) a = fmaf(W_out[k], h2[k], a);
    out[0] = a;
}

extern "C" void kernel_launch(void* const* d_in, const int* in_sizes, int n_in,
                              void* d_out, int out_size, void* d_ws, size_t ws_size,
                              hipStream_t stream) {
    const float* link_state = (const float*)d_in[0];
    const int*   first      = (const int*)  d_in[1];
    const int*   second     = (const int*)  d_in[2];
    // d_in[3] = state_dim (unused)
    const float* W_msg = (const float*)d_in[4];
    const float* b_msg = (const float*)d_in[5];
    const float* W_ih  = (const float*)d_in[6];
    const float* W_hh  = (const float*)d_in[7];
    const float* b_ih  = (const float*)d_in[8];
    const float* b_hh  = (const float*)d_in[9];
    const float* W_r1  = (const float*)d_in[10];
    const float* b_r1  = (const float*)d_in[11];
    const float* W_r2  = (const float*)d_in[12];
    const float* b_r2  = (const float*)d_in[13];
    const float* W_out = (const float*)d_in[14];
    const float* b_out = (const float*)d_in[15];
    float* out = (float*)d_out;

    const size_t NF = (size_t)N_LINKS * F;
    float* state   = (float*)d_ws;                    // 21 MB
    float* X2      = state + NF;                      // 21 MB
    float* agg     = X2 + NF;                         // 21 MB (aliases sortedA)
    unsigned char* X1b = (unsigned char*)(agg + NF);  // 8.4 MB (32B fp8 rows)
    int*    srcs   = (int*)(X1b + (size_t)N_LINKS * XB);  // 16.8 MB
    int*    rs     = srcs + N_PAIRS;                  // 1 MB (+1)
    float* feature = (float*)(rs + N_LINKS + 1);      // 128 B slot
    int* bhist     = (int*)(feature + 32);
    int* bstart    = bhist + NBUCK;                   // NBUCK+1
    int* bcursor   = bstart + NBUCK + 1;
    unsigned* sortedA = (unsigned*)agg;               // lifetime: fill..refine only

    hipMemsetAsync(bhist, 0, NBUCK * sizeof(int), stream);
    hipMemsetAsync(feature, 0, F * sizeof(float), stream);

    k_hist<<<128, 512, 0, stream>>>(second, bhist);
    k_scan<<<1, 1024, 0, stream>>>(bhist, bstart, bcursor, rs);
    k_fill<<<FILL_BLOCKS, FILL_THREADS, 0, stream>>>(first, second, bcursor, sortedA);
    k_refine<<<NBUCK, 256, 0, stream>>>(bstart, sortedA, srcs, rs);

    k_premsg<<<N_LINKS / 256, 256, 0, stream>>>(link_state, W_msg, b_msg, X1b, X2);
    for (int t = 0; t < T_ITERS; ++t) {
        const float* h = (t == 0) ? link_state : state;
        int flags = (t < T_ITERS - 1 ? 1 : 0) | (t == T_ITERS - 1 ? 2 : 0);
        k_agg<<<N_LINKS / 4, 256, 0, stream>>>(rs, srcs, X1b, X2, agg);
        k_gru<<<N_LINKS / 256, 256, 0, stream>>>(agg, h, W_ih, W_hh, b_ih, b_hh,
                                                 W_msg, b_msg, state, X1b, X2,
                                                 feature, flags);
    }
    k_readout<<<1, 64, 0, stream>>>(feature, W_r1, b_r1, W_r2, b_r2, W_out, b_out, out);
}

// Round 8
// 786.186 us; speedup vs baseline: 4.6388x; 1.2812x over previous
//
#include <hip/hip_runtime.h>
#include <hip/hip_fp16.h>

#define N_LINKS 262144
#define N_PAIRS 4194304
#define F 20
#define XB 32                   // X1 fp8 row stride in BYTES (32 B, half a line)
#define T_ITERS 4
#define NBUCK 4096              // buckets of 64 links: bucket = second >> 6
#define LPB 64                  // links per bucket
#define BCAP 2048               // max pairs staged per bucket (mean 1024)

__device__ __forceinline__ float selu_f(float x) {
    const float scale = 1.0507009873554805f;
    const float scale_alpha = 1.7580993408473766f;  // scale * alpha
    return x > 0.0f ? scale * x : scale_alpha * (__expf(x) - 1.0f);
}

// Branchless selu: sa*exp(min(x,0)) - sa + s*max(x,0). Exact at x=0 (exp(0)=1).
__device__ __forceinline__ float selu_b(float x) {
    const float s = 1.0507009873554805f;
    const float sa = 1.7580993408473766f;
    const float mx = fmaxf(x, 0.0f);
    const float mn = fminf(x, 0.0f);
    return fmaf(sa, __expf(mn), fmaf(s, mx, -sa));
}

__device__ __forceinline__ float sigmoid_f(float x) {
    return 1.0f / (1.0f + __expf(-x));
}

__device__ __forceinline__ float tanh_fast(float x) {
    x = fminf(fmaxf(x, -15.0f), 15.0f);
    float e = __expf(2.0f * x);
    return (e - 1.0f) / (e + 1.0f);
}

// Pack 20 floats -> 20 fp8 e4m3 bytes + 12 zero pad, one 32B row (2x int4).
__device__ __forceinline__ void store_row_fp8(unsigned char* rowp, const float* o1) {
    int d[8];
#pragma unroll
    for (int i = 0; i < 5; ++i) {
        int w = 0;
        w = __builtin_amdgcn_cvt_pk_fp8_f32(o1[4*i+0], o1[4*i+1], w, false);
        w = __builtin_amdgcn_cvt_pk_fp8_f32(o1[4*i+2], o1[4*i+3], w, true);
        d[i] = w;
    }
    d[5] = d[6] = d[7] = 0;
    ((int4*)rowp)[0] = make_int4(d[0], d[1], d[2], d[3]);
    ((int4*)rowp)[1] = make_int4(d[4], d[5], d[6], d[7]);
}

// ---------------- CSR build (once per call; graph is static) ----------------

__global__ void k_hist(const int* __restrict__ second, int* __restrict__ bhist) {
    __shared__ int h[NBUCK];
    for (int i = threadIdx.x; i < NBUCK; i += blockDim.x) h[i] = 0;
    __syncthreads();
    for (int p = blockIdx.x * blockDim.x + threadIdx.x; p < N_PAIRS;
         p += gridDim.x * blockDim.x)
        atomicAdd(&h[second[p] >> 6], 1);
    __syncthreads();
    for (int i = threadIdx.x; i < NBUCK; i += blockDim.x) {
        int c = h[i];
        if (c) atomicAdd(&bhist[i], c);
    }
}

__global__ void k_scan(const int* __restrict__ bhist,
                       int* __restrict__ bstart, int* __restrict__ bcursor,
                       int* __restrict__ rs) {
    __shared__ int sums[1024];
    const int tid = threadIdx.x;
    const int b0 = tid * 4;
    int local[4];
    int s = 0;
#pragma unroll
    for (int i = 0; i < 4; ++i) { local[i] = bhist[b0 + i]; s += local[i]; }
    sums[tid] = s;
    __syncthreads();
    for (int off = 1; off < 1024; off <<= 1) {
        int v = (tid >= off) ? sums[tid - off] : 0;
        __syncthreads();
        sums[tid] += v;
        __syncthreads();
    }
    int run = (tid == 0) ? 0 : sums[tid - 1];
#pragma unroll
    for (int i = 0; i < 4; ++i) {
        bstart[b0 + i] = run;
        bcursor[b0 + i] = run;
        run += local[i];
    }
    if (tid == 1023) { bstart[NBUCK] = run; rs[N_LINKS] = run; }
}

// Per-block reservation partition into buckets; entry = {first:18 | dst&63:6}.
#define FILL_BLOCKS 128
#define FILL_THREADS 1024
__global__ void __launch_bounds__(FILL_THREADS)
k_fill(const int* __restrict__ first, const int* __restrict__ second,
       int* __restrict__ bcursor, unsigned* __restrict__ sortedA) {
    __shared__ int h[NBUCK];
    __shared__ int resv[NBUCK];
    const int chunk = N_PAIRS / FILL_BLOCKS;   // 32768
    const int base = blockIdx.x * chunk;
    for (int i = threadIdx.x; i < NBUCK; i += blockDim.x) h[i] = 0;
    __syncthreads();
    for (int i = threadIdx.x; i < chunk; i += blockDim.x)
        atomicAdd(&h[second[base + i] >> 6], 1);
    __syncthreads();
    for (int i = threadIdx.x; i < NBUCK; i += blockDim.x) {
        int c = h[i];
        resv[i] = c ? atomicAdd(&bcursor[i], c) : 0;
        h[i] = 0;  // reuse as local cursor
    }
    __syncthreads();
    for (int i = threadIdx.x; i < chunk; i += blockDim.x) {
        int s = second[base + i];
        int b = s >> 6;
        int pos = resv[b] + atomicAdd(&h[b], 1);
        sortedA[pos] = (unsigned)first[base + i] | ((unsigned)(s & 63) << 18);
    }
}

// One block per bucket: in-LDS counting sort -> per-link CSR (rs + srcs).
__global__ void __launch_bounds__(256)
k_refine(const int* __restrict__ bstart, const unsigned* __restrict__ sortedA,
         int* __restrict__ srcs, int* __restrict__ rs) {
    __shared__ unsigned ent[BCAP];
    __shared__ int outv[BCAP];
    __shared__ int cnt[LPB];
    __shared__ int off[LPB];
    const int b = blockIdx.x;
    const int s = bstart[b];
    int n = bstart[b + 1] - s;
    if (n > BCAP) n = BCAP;  // statistically impossible (mean 1024, 30+ sigma)
    for (int i = threadIdx.x; i < n; i += 256) ent[i] = sortedA[s + i];
    if (threadIdx.x < LPB) cnt[threadIdx.x] = 0;
    __syncthreads();
    for (int i = threadIdx.x; i < n; i += 256)
        atomicAdd(&cnt[ent[i] >> 18], 1);
    __syncthreads();
    if (threadIdx.x < LPB) {
        int acc = 0;
        for (int j = 0; j < threadIdx.x; ++j) acc += cnt[j];
        off[threadIdx.x] = acc;
        rs[b * LPB + threadIdx.x] = s + acc;
    }
    __syncthreads();
    for (int i = threadIdx.x; i < n; i += 256) {
        unsigned v = ent[i];
        int pos = atomicAdd(&off[v >> 18], 1);
        outv[pos] = (int)(v & 0x3FFFF);
    }
    __syncthreads();
    for (int i = threadIdx.x; i < n; i += 256) srcs[s + i] = outv[i];
}

// ---------------- per-iteration kernels ----------------

// X1b[l] = fp8(W1 @ state[l] + b_msg), 32B rows ; X2[l] = W2 @ state[l]
__global__ void k_premsg(const float* __restrict__ state,
                         const float* __restrict__ W_msg,
                         const float* __restrict__ b_msg,
                         unsigned char* __restrict__ X1b, float* __restrict__ X2) {
    __shared__ float Wl[F * 2 * F];
    __shared__ float bl[F];
    for (int i = threadIdx.x; i < F * 2 * F; i += blockDim.x) Wl[i] = W_msg[i];
    if (threadIdx.x < F) bl[threadIdx.x] = b_msg[threadIdx.x];
    __syncthreads();

    int l = blockIdx.x * blockDim.x + threadIdx.x;

    float s[F];
    const float4* sp = (const float4*)(state + (size_t)l * F);
#pragma unroll
    for (int i = 0; i < 5; ++i) {
        float4 v = sp[i];
        s[4*i+0] = v.x; s[4*i+1] = v.y; s[4*i+2] = v.z; s[4*i+3] = v.w;
    }
    float o1[F], o2[F];
#pragma unroll
    for (int o = 0; o < F; ++o) {
        float a1 = bl[o], a2 = 0.0f;
#pragma unroll
        for (int k = 0; k < F; ++k) {
            a1 = fmaf(Wl[o * 2 * F + k],     s[k], a1);
            a2 = fmaf(Wl[o * 2 * F + F + k], s[k], a2);
        }
        o1[o] = a1; o2[o] = a2;
    }
    store_row_fp8(X1b + (size_t)l * XB, o1);
    float4* x2p = (float4*)(X2 + (size_t)l * F);
#pragma unroll
    for (int i = 0; i < 5; ++i)
        x2p[i] = make_float4(o2[4*i], o2[4*i+1], o2[4*i+2], o2[4*i+3]);
}

// Wave-per-link gather-aggregate, instruction-diet layout:
// lane = sub*16 + j: group `sub` (0..3) handles pair i = 4r+sub of this link;
// lane j covers features 2j, 2j+1 (ushort = 2 fp8 bytes of the 32B row; rows
// zero-padded past f=19 and x2 zeroed for pad lanes so selu_b contributes 0).
// Main loop (R = cnt>>2 rounds) has NO guards/bpermute; one guarded tail round.
__global__ void __launch_bounds__(256)
k_agg(const int* __restrict__ rs, const int* __restrict__ srcs,
      const unsigned char* __restrict__ X1b, const float* __restrict__ X2,
      float* __restrict__ agg) {
    const int wave = threadIdx.x >> 6;
    const int l = blockIdx.x * 4 + wave;
    const int lane = threadIdx.x & 63;
    const int j = lane & 15;          // feature pair: features 2j, 2j+1
    const int sub = lane >> 4;        // pair group: pair index i = 4r + sub

    const int row_start = rs[l];
    const int cnt = rs[l + 1] - row_start;

    float x2a = 0.0f, x2b = 0.0f;
    if (j < 10) {
        const float2 v = *(const float2*)(X2 + (size_t)l * F + 2 * j);
        x2a = v.x; x2b = v.y;
    }

    const int* sp = srcs + row_start;
    float acc_a = 0.0f, acc_b = 0.0f;

    const int R = cnt >> 2;           // pairs 4r+sub < 4R <= cnt: always valid
#pragma unroll 4
    for (int r = 0; r < R; ++r) {
        const int src = sp[(r << 2) + sub];
        const int v = *(const unsigned short*)(X1b + ((size_t)src << 5) + 2 * j);
        const float xa = __builtin_amdgcn_cvt_f32_fp8(v, 0) + x2a;
        const float xb = __builtin_amdgcn_cvt_f32_fp8(v, 1) + x2b;
        acc_a += selu_b(xa);
        acc_b += selu_b(xb);
    }
    if ((R << 2) < cnt) {             // tail round (wave-uniform branch)
        const int i = (R << 2) + sub;
        const int src = sp[min(i, cnt - 1)];
        const int v = *(const unsigned short*)(X1b + ((size_t)src << 5) + 2 * j);
        const float xa = __builtin_amdgcn_cvt_f32_fp8(v, 0) + x2a;
        const float xb = __builtin_amdgcn_cvt_f32_fp8(v, 1) + x2b;
        const bool ok = i < cnt;
        acc_a += ok ? selu_b(xa) : 0.0f;
        acc_b += ok ? selu_b(xb) : 0.0f;
    }
    // sum the 4 pair-groups (lanes j, j+16, j+32, j+48)
    acc_a += __shfl_xor(acc_a, 32, 64);
    acc_a += __shfl_xor(acc_a, 16, 64);
    acc_b += __shfl_xor(acc_b, 32, 64);
    acc_b += __shfl_xor(acc_b, 16, 64);
    if (lane < 10) {                  // sub==0, j<10: write features 2j, 2j+1
        float2 o; o.x = acc_a; o.y = acc_b;
        *(float2*)(agg + (size_t)l * F + 2 * j) = o;
    }
}

// GRU fused with next-iteration premsg (flags&1) and feature reduce (flags&2).
__global__ void __launch_bounds__(256)
k_gru(const float* __restrict__ agg, const float* __restrict__ h_in,
      const float* __restrict__ W_ih, const float* __restrict__ W_hh,
      const float* __restrict__ b_ih, const float* __restrict__ b_hh,
      const float* __restrict__ W_msg, const float* __restrict__ b_msg,
      float* __restrict__ h_out, unsigned char* __restrict__ X1b,
      float* __restrict__ X2, float* __restrict__ feature, int flags) {
    __shared__ float Wi[3 * F * F];
    __shared__ float Wh[3 * F * F];
    __shared__ float Wm[F * 2 * F];
    __shared__ float bi[3 * F];
    __shared__ float bh[3 * F];
    __shared__ float bm[F];
    __shared__ float red[4 * F];
    for (int i = threadIdx.x; i < 3 * F * F; i += blockDim.x) {
        Wi[i] = W_ih[i];
        Wh[i] = W_hh[i];
    }
    for (int i = threadIdx.x; i < F * 2 * F; i += blockDim.x) Wm[i] = W_msg[i];
    if (threadIdx.x < 3 * F) {
        bi[threadIdx.x] = b_ih[threadIdx.x];
        bh[threadIdx.x] = b_hh[threadIdx.x];
    }
    if (threadIdx.x < F) bm[threadIdx.x] = b_msg[threadIdx.x];
    __syncthreads();

    const int l = blockIdx.x * blockDim.x + threadIdx.x;

    float m[F], h[F];
    const float4* mp = (const float4*)(agg  + (size_t)l * F);
    const float4* hp = (const float4*)(h_in + (size_t)l * F);
#pragma unroll
    for (int i = 0; i < 5; ++i) {
        float4 vm = mp[i], vh = hp[i];
        m[4*i+0] = vm.x; m[4*i+1] = vm.y; m[4*i+2] = vm.z; m[4*i+3] = vm.w;
        h[4*i+0] = vh.x; h[4*i+1] = vh.y; h[4*i+2] = vh.z; h[4*i+3] = vh.w;
    }

    float hn[F];
#pragma unroll
    for (int j = 0; j < F; ++j) {
        float gr = bi[j]     + bh[j];
        float gz = bi[F + j] + bh[F + j];
        float gi_n = bi[2*F + j];
        float gh_n = bh[2*F + j];
        float gr_i = 0.f, gz_i = 0.f, gr_h = 0.f, gz_h = 0.f;
#pragma unroll
        for (int k = 0; k < F; ++k) {
            gr_i = fmaf(Wi[(0*F + j) * F + k], m[k], gr_i);
            gz_i = fmaf(Wi[(1*F + j) * F + k], m[k], gz_i);
            gi_n = fmaf(Wi[(2*F + j) * F + k], m[k], gi_n);
            gr_h = fmaf(Wh[(0*F + j) * F + k], h[k], gr_h);
            gz_h = fmaf(Wh[(1*F + j) * F + k], h[k], gz_h);
            gh_n = fmaf(Wh[(2*F + j) * F + k], h[k], gh_n);
        }
        float r = sigmoid_f(gr + gr_i + gr_h);
        float z = sigmoid_f(gz + gz_i + gz_h);
        float n = tanh_fast(gi_n + r * gh_n);
        hn[j] = (1.0f - z) * n + z * h[j];
    }

    float4* op = (float4*)(h_out + (size_t)l * F);
#pragma unroll
    for (int i = 0; i < 5; ++i)
        op[i] = make_float4(hn[4*i], hn[4*i+1], hn[4*i+2], hn[4*i+3]);

    if (flags & 1) {  // premsg for next iteration from hn
        float o1[F], o2[F];
#pragma unroll
        for (int o = 0; o < F; ++o) {
            float a1 = bm[o], a2 = 0.0f;
#pragma unroll
            for (int k = 0; k < F; ++k) {
                a1 = fmaf(Wm[o * 2 * F + k],     hn[k], a1);
                a2 = fmaf(Wm[o * 2 * F + F + k], hn[k], a2);
            }
            o1[o] = a1; o2[o] = a2;
        }
        store_row_fp8(X1b + (size_t)l * XB, o1);
        float4* x2p = (float4*)(X2 + (size_t)l * F);
#pragma unroll
        for (int i = 0; i < 5; ++i)
            x2p[i] = make_float4(o2[4*i], o2[4*i+1], o2[4*i+2], o2[4*i+3]);
    }

    if (flags & 2) {  // feature reduction: sum hn over all links
#pragma unroll
        for (int off = 1; off < 64; off <<= 1) {
#pragma unroll
            for (int j = 0; j < F; ++j) hn[j] += __shfl_xor(hn[j], off, 64);
        }
        const int lane = threadIdx.x & 63;
        const int wave = threadIdx.x >> 6;
        if (lane == 0) {
#pragma unroll
            for (int j = 0; j < F; ++j) red[wave * F + j] = hn[j];
        }
        __syncthreads();
        if (threadIdx.x < F) {
            float s = red[threadIdx.x] + red[F + threadIdx.x] +
                      red[2 * F + threadIdx.x] + red[3 * F + threadIdx.x];
            atomicAdd(&feature[threadIdx.x], s);
        }
    }
}

__global__ void k_readout(const float* __restrict__ feature,
                          const float* __restrict__ W_r1, const float* __restrict__ b_r1,
                          const float* __restrict__ W_r2, const float* __restrict__ b_r2,
                          const float* __restrict__ W_out, const float* __restrict__ b_out,
                          float* __restrict__ out) {
    if (threadIdx.x != 0 || blockIdx.x != 0) return;
    float fv[F], h1[F], h2[F];
#pragma unroll
    for (int i = 0; i < F; ++i) fv[i] = feature[i];
#pragma unroll
    for (int o = 0; o < F; ++o) {
        float a = b_r1[o];
#pragma unroll
        for (int k = 0; k < F; ++k) a = fmaf(W_r1[o * F + k], fv[k], a);
        h1[o] = selu_f(a);
    }
#pragma unroll
    for (int o = 0; o < F; ++o) {
        float a = b_r2[o];
#pragma unroll
        for (int k = 0; k < F; ++k) a = fmaf(W_r2[o * F + k], h1[k], a);
        h2[o] = selu_f(a);
    }
    float a = b_out[0];
#pragma unroll
    for (int k = 0; k < F; ++k) a = fmaf(W_out[k], h2[k], a);
    out[0] = a;
}

extern "C" void kernel_launch(void* const* d_in, const int* in_sizes, int n_in,
                              void* d_out, int out_size, void* d_ws, size_t ws_size,
                              hipStream_t stream) {
    const float* link_state = (const float*)d_in[0];
    const int*   first      = (const int*)  d_in[1];
    const int*   second     = (const int*)  d_in[2];
    // d_in[3] = state_dim (unused)
    const float* W_msg = (const float*)d_in[4];
    const float* b_msg = (const float*)d_in[5];
    const float* W_ih  = (const float*)d_in[6];
    const float* W_hh  = (const float*)d_in[7];
    const float* b_ih  = (const float*)d_in[8];
    const float* b_hh  = (const float*)d_in[9];
    const float* W_r1  = (const float*)d_in[10];
    const float* b_r1  = (const float*)d_in[11];
    const float* W_r2  = (const float*)d_in[12];
    const float* b_r2  = (const float*)d_in[13];
    const float* W_out = (const float*)d_in[14];
    const float* b_out = (const float*)d_in[15];
    float* out = (float*)d_out;

    const size_t NF = (size_t)N_LINKS * F;
    float* state   = (float*)d_ws;                    // 21 MB
    float* X2      = state + NF;                      // 21 MB
    float* agg     = X2 + NF;                         // 21 MB (aliases sortedA)
    unsigned char* X1b = (unsigned char*)(agg + NF);  // 8.4 MB (32B fp8 rows)
    int*    srcs   = (int*)(X1b + (size_t)N_LINKS * XB);  // 16.8 MB
    int*    rs     = srcs + N_PAIRS;                  // 1 MB (+1)
    float* feature = (float*)(rs + N_LINKS + 1);      // 128 B slot
    int* bhist     = (int*)(feature + 32);
    int* bstart    = bhist + NBUCK;                   // NBUCK+1
    int* bcursor   = bstart + NBUCK + 1;
    unsigned* sortedA = (unsigned*)agg;               // lifetime: fill..refine only

    hipMemsetAsync(bhist, 0, NBUCK * sizeof(int), stream);
    hipMemsetAsync(feature, 0, F * sizeof(float), stream);

    k_hist<<<128, 512, 0, stream>>>(second, bhist);
    k_scan<<<1, 1024, 0, stream>>>(bhist, bstart, bcursor, rs);
    k_fill<<<FILL_BLOCKS, FILL_THREADS, 0, stream>>>(first, second, bcursor, sortedA);
    k_refine<<<NBUCK, 256, 0, stream>>>(bstart, sortedA, srcs, rs);

    k_premsg<<<N_LINKS / 256, 256, 0, stream>>>(link_state, W_msg, b_msg, X1b, X2);
    for (int t = 0; t < T_ITERS; ++t) {
        const float* h = (t == 0) ? link_state : state;
        int flags = (t < T_ITERS - 1 ? 1 : 0) | (t == T_ITERS - 1 ? 2 : 0);
        k_agg<<<N_LINKS / 4, 256, 0, stream>>>(rs, srcs, X1b, X2, agg);
        k_gru<<<N_LINKS / 256, 256, 0, stream>>>(agg, h, W_ih, W_hh, b_ih, b_hh,
                                                 W_msg, b_msg, state, X1b, X2,
                                                 feature, flags);
    }
    k_readout<<<1, 64, 0, stream>>>(feature, W_r1, b_r1, W_r2, b_r2, W_out, b_out, out);
}

// Round 9
// 780.682 us; speedup vs baseline: 4.6715x; 1.0071x over previous
//
#include <hip/hip_runtime.h>
#include <hip/hip_fp16.h>

#define N_LINKS 262144
#define N_PAIRS 4194304
#define F 20
#define XB 32                   // X1 fp8 row stride in BYTES (32 B, half a line)
#define T_ITERS 4

#define NSB 256                 // sectors (CSR build): sector = link >> 10
#define LPS 1024                // links per sector
#define PB 128                  // partition blocks
#define PT 1024                 // partition threads
#define PCHUNK (N_PAIRS / PB)   // 32768 pairs per partition block
#define PPT (PCHUNK / PT)       // 32 pairs per thread

__device__ __forceinline__ float selu_f(float x) {
    const float scale = 1.0507009873554805f;
    const float scale_alpha = 1.7580993408473766f;  // scale * alpha
    return x > 0.0f ? scale * x : scale_alpha * (__expf(x) - 1.0f);
}

// Branchless selu: sa*exp(min(x,0)) - sa + s*max(x,0). Exact at x=0 (exp(0)=1).
__device__ __forceinline__ float selu_b(float x) {
    const float s = 1.0507009873554805f;
    const float sa = 1.7580993408473766f;
    const float mx = fmaxf(x, 0.0f);
    const float mn = fminf(x, 0.0f);
    return fmaf(sa, __expf(mn), fmaf(s, mx, -sa));
}

__device__ __forceinline__ float sigmoid_f(float x) {
    return 1.0f / (1.0f + __expf(-x));
}

__device__ __forceinline__ float tanh_fast(float x) {
    x = fminf(fmaxf(x, -15.0f), 15.0f);
    float e = __expf(2.0f * x);
    return (e - 1.0f) / (e + 1.0f);
}

// Pack 20 floats -> 20 fp8 e4m3 bytes + 12 zero pad, one 32B row (2x int4).
__device__ __forceinline__ void store_row_fp8(unsigned char* rowp, const float* o1) {
    int d[8];
#pragma unroll
    for (int i = 0; i < 5; ++i) {
        int w = 0;
        w = __builtin_amdgcn_cvt_pk_fp8_f32(o1[4*i+0], o1[4*i+1], w, false);
        w = __builtin_amdgcn_cvt_pk_fp8_f32(o1[4*i+2], o1[4*i+3], w, true);
        d[i] = w;
    }
    d[5] = d[6] = d[7] = 0;
    ((int4*)rowp)[0] = make_int4(d[0], d[1], d[2], d[3]);
    ((int4*)rowp)[1] = make_int4(d[4], d[5], d[6], d[7]);
}

// ---------------- CSR build (once per call; graph is static) ----------------

// Each block counting-sorts its 32K-pair chunk by sector into its OWN window
// of `ent` (single-block window -> single-XCD L2 -> no cross-XCD write
// amplification). Emits per-(block,sector) offsets + global sector totals.
// Entry = {first:18 | link-within-sector:10}.
__global__ void __launch_bounds__(PT)
k_part(const int* __restrict__ first, const int* __restrict__ second,
       int* __restrict__ ent, int* __restrict__ ptable, int* __restrict__ sectot) {
    __shared__ int hist[NSB];
    __shared__ int cur[NSB];
    const int b = blockIdx.x;
    const int cbase = b * PCHUNK;
    const int tid = threadIdx.x;
    for (int i = tid; i < NSB; i += PT) hist[i] = 0;
    __syncthreads();
    int sv[PPT];
#pragma unroll
    for (int k = 0; k < PPT; ++k) {
        sv[k] = second[cbase + k * PT + tid];
        atomicAdd(&hist[sv[k] >> 10], 1);
    }
    __syncthreads();
    if (tid < NSB) {
        int acc = 0;
        for (int j = 0; j < tid; ++j) acc += hist[j];   // excl scan, 256 bins
        cur[tid] = acc;
        ptable[b * (NSB + 1) + tid] = acc;
        if (tid == 0) ptable[b * (NSB + 1) + NSB] = PCHUNK;
        atomicAdd(&sectot[tid], hist[tid]);
    }
    __syncthreads();
#pragma unroll
    for (int k = 0; k < PPT; ++k) {
        const int s = sv[k];
        const int f = first[cbase + k * PT + tid];
        const int pos = atomicAdd(&cur[s >> 10], 1);
        ent[cbase + pos] = f | ((s & 1023) << 18);
    }
}

// Exact exclusive scan of 256 sector totals -> sector bases (srcs contiguous).
__global__ void k_scan256(const int* __restrict__ sectot, int* __restrict__ sbase,
                          int* __restrict__ rs) {
    __shared__ int s[NSB];
    const int t = threadIdx.x;
    s[t] = sectot[t];
    __syncthreads();
    if (t == 0) {
        int acc = 0;
        for (int j = 0; j < NSB; ++j) { int c = s[j]; s[j] = acc; acc += c; }
    }
    __syncthreads();
    sbase[t] = s[t];
    if (t == 0) { sbase[NSB] = N_PAIRS; rs[N_LINKS] = N_PAIRS; }
}

// One block per sector: gather the sector's entries from the 128 table-addressed
// runs, per-link LDS histogram + scan -> rs, then scatter srcs into the
// sector's private contiguous window (single-XCD writes).
__global__ void __launch_bounds__(PT)
k_build(const int* __restrict__ ptable, const int* __restrict__ sbase,
        const int* __restrict__ ent, int* __restrict__ srcs, int* __restrict__ rs) {
    __shared__ int rstart[PB];
    __shared__ int rlen[PB];
    __shared__ int lcnt[LPS];
    __shared__ int lown[LPS];
    __shared__ int cur[LPS];
    const int sb = blockIdx.x;
    const int tid = threadIdx.x;
    if (tid < PB) {
        const int o0 = ptable[tid * (NSB + 1) + sb];
        const int o1 = ptable[tid * (NSB + 1) + sb + 1];
        rstart[tid] = tid * PCHUNK + o0;
        rlen[tid] = o1 - o0;
    }
    lcnt[tid] = 0;                       // PT == LPS
    __syncthreads();
    const int wave = tid >> 6;
    const int lane = tid & 63;
    for (int j = wave; j < PB; j += (PT >> 6)) {
        const int r0 = rstart[j], rl = rlen[j];
        for (int i = lane; i < rl; i += 64)
            atomicAdd(&lcnt[(ent[r0 + i] >> 18) & 1023], 1);
    }
    __syncthreads();
    const int own = lcnt[tid];
    lown[tid] = own;
    for (int off = 1; off < LPS; off <<= 1) {   // inclusive Hillis-Steele
        const int v = (tid >= off) ? lcnt[tid - off] : 0;
        __syncthreads();
        lcnt[tid] += v;
        __syncthreads();
    }
    const int sbb = sbase[sb];
    const int excl = lcnt[tid] - lown[tid];
    rs[sb * LPS + tid] = sbb + excl;
    cur[tid] = excl;
    __syncthreads();
    for (int j = wave; j < PB; j += (PT >> 6)) {
        const int r0 = rstart[j], rl = rlen[j];
        for (int i = lane; i < rl; i += 64) {
            const int e = ent[r0 + i];
            const int pos = atomicAdd(&cur[(e >> 18) & 1023], 1);
            srcs[sbb + pos] = e & 0x3FFFF;
        }
    }
}

// ---------------- per-iteration kernels ----------------

// X1b[l] = fp8(W1 @ state[l] + b_msg), 32B rows ; X2[l] = W2 @ state[l]
__global__ void k_premsg(const float* __restrict__ state,
                         const float* __restrict__ W_msg,
                         const float* __restrict__ b_msg,
                         unsigned char* __restrict__ X1b, float* __restrict__ X2) {
    __shared__ float Wl[F * 2 * F];
    __shared__ float bl[F];
    for (int i = threadIdx.x; i < F * 2 * F; i += blockDim.x) Wl[i] = W_msg[i];
    if (threadIdx.x < F) bl[threadIdx.x] = b_msg[threadIdx.x];
    __syncthreads();

    int l = blockIdx.x * blockDim.x + threadIdx.x;

    float s[F];
    const float4* sp = (const float4*)(state + (size_t)l * F);
#pragma unroll
    for (int i = 0; i < 5; ++i) {
        float4 v = sp[i];
        s[4*i+0] = v.x; s[4*i+1] = v.y; s[4*i+2] = v.z; s[4*i+3] = v.w;
    }
    float o1[F], o2[F];
#pragma unroll
    for (int o = 0; o < F; ++o) {
        float a1 = bl[o], a2 = 0.0f;
#pragma unroll
        for (int k = 0; k < F; ++k) {
            a1 = fmaf(Wl[o * 2 * F + k],     s[k], a1);
            a2 = fmaf(Wl[o * 2 * F + F + k], s[k], a2);
        }
        o1[o] = a1; o2[o] = a2;
    }
    store_row_fp8(X1b + (size_t)l * XB, o1);
    float4* x2p = (float4*)(X2 + (size_t)l * F);
#pragma unroll
    for (int i = 0; i < 5; ++i)
        x2p[i] = make_float4(o2[4*i], o2[4*i+1], o2[4*i+2], o2[4*i+3]);
}

// Wave-per-link gather-aggregate, instruction-diet layout:
// lane = sub*16 + j: group `sub` (0..3) handles pair i = 4r+sub of this link;
// lane j covers features 2j, 2j+1 (ushort = 2 fp8 bytes of the 32B row; rows
// zero-padded past f=19 and x2 zeroed for pad lanes so selu_b contributes 0).
// Main loop (R = cnt>>2 rounds) has NO guards/bpermute; one guarded tail round.
__global__ void __launch_bounds__(256)
k_agg(const int* __restrict__ rs, const int* __restrict__ srcs,
      const unsigned char* __restrict__ X1b, const float* __restrict__ X2,
      float* __restrict__ agg) {
    const int wave = threadIdx.x >> 6;
    const int l = blockIdx.x * 4 + wave;
    const int lane = threadIdx.x & 63;
    const int j = lane & 15;          // feature pair: features 2j, 2j+1
    const int sub = lane >> 4;        // pair group: pair index i = 4r + sub

    const int row_start = rs[l];
    const int cnt = rs[l + 1] - row_start;

    float x2a = 0.0f, x2b = 0.0f;
    if (j < 10) {
        const float2 v = *(const float2*)(X2 + (size_t)l * F + 2 * j);
        x2a = v.x; x2b = v.y;
    }

    const int* sp = srcs + row_start;
    float acc_a = 0.0f, acc_b = 0.0f;

    const int R = cnt >> 2;           // pairs 4r+sub < 4R <= cnt: always valid
#pragma unroll 4
    for (int r = 0; r < R; ++r) {
        const int src = sp[(r << 2) + sub];
        const int v = *(const unsigned short*)(X1b + ((size_t)src << 5) + 2 * j);
        const float xa = __builtin_amdgcn_cvt_f32_fp8(v, 0) + x2a;
        const float xb = __builtin_amdgcn_cvt_f32_fp8(v, 1) + x2b;
        acc_a += selu_b(xa);
        acc_b += selu_b(xb);
    }
    if ((R << 2) < cnt) {             // tail round (wave-uniform branch)
        const int i = (R << 2) + sub;
        const int src = sp[min(i, cnt - 1)];
        const int v = *(const unsigned short*)(X1b + ((size_t)src << 5) + 2 * j);
        const float xa = __builtin_amdgcn_cvt_f32_fp8(v, 0) + x2a;
        const float xb = __builtin_amdgcn_cvt_f32_fp8(v, 1) + x2b;
        const bool ok = i < cnt;
        acc_a += ok ? selu_b(xa) : 0.0f;
        acc_b += ok ? selu_b(xb) : 0.0f;
    }
    // sum the 4 pair-groups (lanes j, j+16, j+32, j+48)
    acc_a += __shfl_xor(acc_a, 32, 64);
    acc_a += __shfl_xor(acc_a, 16, 64);
    acc_b += __shfl_xor(acc_b, 32, 64);
    acc_b += __shfl_xor(acc_b, 16, 64);
    if (lane < 10) {                  // sub==0, j<10: write features 2j, 2j+1
        float2 o; o.x = acc_a; o.y = acc_b;
        *(float2*)(agg + (size_t)l * F + 2 * j) = o;
    }
}

// GRU fused with next-iteration premsg (flags&1) and feature reduce (flags&2).
__global__ void __launch_bounds__(256)
k_gru(const float* __restrict__ agg, const float* __restrict__ h_in,
      const float* __restrict__ W_ih, const float* __restrict__ W_hh,
      const float* __restrict__ b_ih, const float* __restrict__ b_hh,
      const float* __restrict__ W_msg, const float* __restrict__ b_msg,
      float* __restrict__ h_out, unsigned char* __restrict__ X1b,
      float* __restrict__ X2, float* __restrict__ feature, int flags) {
    __shared__ float Wi[3 * F * F];
    __shared__ float Wh[3 * F * F];
    __shared__ float Wm[F * 2 * F];
    __shared__ float bi[3 * F];
    __shared__ float bh[3 * F];
    __shared__ float bm[F];
    __shared__ float red[4 * F];
    for (int i = threadIdx.x; i < 3 * F * F; i += blockDim.x) {
        Wi[i] = W_ih[i];
        Wh[i] = W_hh[i];
    }
    for (int i = threadIdx.x; i < F * 2 * F; i += blockDim.x) Wm[i] = W_msg[i];
    if (threadIdx.x < 3 * F) {
        bi[threadIdx.x] = b_ih[threadIdx.x];
        bh[threadIdx.x] = b_hh[threadIdx.x];
    }
    if (threadIdx.x < F) bm[threadIdx.x] = b_msg[threadIdx.x];
    __syncthreads();

    const int l = blockIdx.x * blockDim.x + threadIdx.x;

    float m[F], h[F];
    const float4* mp = (const float4*)(agg  + (size_t)l * F);
    const float4* hp = (const float4*)(h_in + (size_t)l * F);
#pragma unroll
    for (int i = 0; i < 5; ++i) {
        float4 vm = mp[i], vh = hp[i];
        m[4*i+0] = vm.x; m[4*i+1] = vm.y; m[4*i+2] = vm.z; m[4*i+3] = vm.w;
        h[4*i+0] = vh.x; h[4*i+1] = vh.y; h[4*i+2] = vh.z; h[4*i+3] = vh.w;
    }

    float hn[F];
#pragma unroll
    for (int j = 0; j < F; ++j) {
        float gr = bi[j]     + bh[j];
        float gz = bi[F + j] + bh[F + j];
        float gi_n = bi[2*F + j];
        float gh_n = bh[2*F + j];
        float gr_i = 0.f, gz_i = 0.f, gr_h = 0.f, gz_h = 0.f;
#pragma unroll
        for (int k = 0; k < F; ++k) {
            gr_i = fmaf(Wi[(0*F + j) * F + k], m[k], gr_i);
            gz_i = fmaf(Wi[(1*F + j) * F + k], m[k], gz_i);
            gi_n = fmaf(Wi[(2*F + j) * F + k], m[k], gi_n);
            gr_h = fmaf(Wh[(0*F + j) * F + k], h[k], gr_h);
            gz_h = fmaf(Wh[(1*F + j) * F + k], h[k], gz_h);
            gh_n = fmaf(Wh[(2*F + j) * F + k], h[k], gh_n);
        }
        float r = sigmoid_f(gr + gr_i + gr_h);
        float z = sigmoid_f(gz + gz_i + gz_h);
        float n = tanh_fast(gi_n + r * gh_n);
        hn[j] = (1.0f - z) * n + z * h[j];
    }

    float4* op = (float4*)(h_out + (size_t)l * F);
#pragma unroll
    for (int i = 0; i < 5; ++i)
        op[i] = make_float4(hn[4*i], hn[4*i+1], hn[4*i+2], hn[4*i+3]);

    if (flags & 1) {  // premsg for next iteration from hn
        float o1[F], o2[F];
#pragma unroll
        for (int o = 0; o < F; ++o) {
            float a1 = bm[o], a2 = 0.0f;
#pragma unroll
            for (int k = 0; k < F; ++k) {
                a1 = fmaf(Wm[o * 2 * F + k],     hn[k], a1);
                a2 = fmaf(Wm[o * 2 * F + F + k], hn[k], a2);
            }
            o1[o] = a1; o2[o] = a2;
        }
        store_row_fp8(X1b + (size_t)l * XB, o1);
        float4* x2p = (float4*)(X2 + (size_t)l * F);
#pragma unroll
        for (int i = 0; i < 5; ++i)
            x2p[i] = make_float4(o2[4*i], o2[4*i+1], o2[4*i+2], o2[4*i+3]);
    }

    if (flags & 2) {  // feature reduction: sum hn over all links
#pragma unroll
        for (int off = 1; off < 64; off <<= 1) {
#pragma unroll
            for (int j = 0; j < F; ++j) hn[j] += __shfl_xor(hn[j], off, 64);
        }
        const int lane = threadIdx.x & 63;
        const int wave = threadIdx.x >> 6;
        if (lane == 0) {
#pragma unroll
            for (int j = 0; j < F; ++j) red[wave * F + j] = hn[j];
        }
        __syncthreads();
        if (threadIdx.x < F) {
            float s = red[threadIdx.x] + red[F + threadIdx.x] +
                      red[2 * F + threadIdx.x] + red[3 * F + threadIdx.x];
            atomicAdd(&feature[threadIdx.x], s);
        }
    }
}

__global__ void k_readout(const float* __restrict__ feature,
                          const float* __restrict__ W_r1, const float* __restrict__ b_r1,
                          const float* __restrict__ W_r2, const float* __restrict__ b_r2,
                          const float* __restrict__ W_out, const float* __restrict__ b_out,
                          float* __restrict__ out) {
    if (threadIdx.x != 0 || blockIdx.x != 0) return;
    float fv[F], h1[F], h2[F];
#pragma unroll
    for (int i = 0; i < F; ++i) fv[i] = feature[i];
#pragma unroll
    for (int o = 0; o < F; ++o) {
        float a = b_r1[o];
#pragma unroll
        for (int k = 0; k < F; ++k) a = fmaf(W_r1[o * F + k], fv[k], a);
        h1[o] = selu_f(a);
    }
#pragma unroll
    for (int o = 0; o < F; ++o) {
        float a = b_r2[o];
#pragma unroll
        for (int k = 0; k < F; ++k) a = fmaf(W_r2[o * F + k], h1[k], a);
        h2[o] = selu_f(a);
    }
    float a = b_out[0];
#pragma unroll
    for (int k = 0; k < F; ++k) a = fmaf(W_out[k], h2[k], a);
    out[0] = a;
}

extern "C" void kernel_launch(void* const* d_in, const int* in_sizes, int n_in,
                              void* d_out, int out_size, void* d_ws, size_t ws_size,
                              hipStream_t stream) {
    const float* link_state = (const float*)d_in[0];
    const int*   first      = (const int*)  d_in[1];
    const int*   second     = (const int*)  d_in[2];
    // d_in[3] = state_dim (unused)
    const float* W_msg = (const float*)d_in[4];
    const float* b_msg = (const float*)d_in[5];
    const float* W_ih  = (const float*)d_in[6];
    const float* W_hh  = (const float*)d_in[7];
    const float* b_ih  = (const float*)d_in[8];
    const float* b_hh  = (const float*)d_in[9];
    const float* W_r1  = (const float*)d_in[10];
    const float* b_r1  = (const float*)d_in[11];
    const float* W_r2  = (const float*)d_in[12];
    const float* b_r2  = (const float*)d_in[13];
    const float* W_out = (const float*)d_in[14];
    const float* b_out = (const float*)d_in[15];
    float* out = (float*)d_out;

    const size_t NF = (size_t)N_LINKS * F;
    float* state   = (float*)d_ws;                    // 21 MB
    float* X2      = state + NF;                      // 21 MB
    float* agg     = X2 + NF;                         // 21 MB (aliases ent)
    unsigned char* X1b = (unsigned char*)(agg + NF);  // 8.4 MB (32B fp8 rows)
    int*    srcs   = (int*)(X1b + (size_t)N_LINKS * XB);  // 16.8 MB
    int*    rs     = srcs + N_PAIRS;                  // 1 MB (+1)
    float* feature = (float*)(rs + N_LINKS + 1);      // 128 B slot
    int* ptable    = (int*)(feature + 32);            // 128*(256+1) ints
    int* sectot    = ptable + PB * (NSB + 1);         // 256 ints
    int* sbase     = sectot + NSB;                    // 257 ints
    int* ent       = (int*)agg;                       // lifetime: part..build only

    hipMemsetAsync(sectot, 0, NSB * sizeof(int), stream);
    hipMemsetAsync(feature, 0, F * sizeof(float), stream);

    k_part<<<PB, PT, 0, stream>>>(first, second, ent, ptable, sectot);
    k_scan256<<<1, NSB, 0, stream>>>(sectot, sbase, rs);
    k_build<<<NSB, PT, 0, stream>>>(ptable, sbase, ent, srcs, rs);

    k_premsg<<<N_LINKS / 256, 256, 0, stream>>>(link_state, W_msg, b_msg, X1b, X2);
    for (int t = 0; t < T_ITERS; ++t) {
        const float* h = (t == 0) ? link_state : state;
        int flags = (t < T_ITERS - 1 ? 1 : 0) | (t == T_ITERS - 1 ? 2 : 0);
        k_agg<<<N_LINKS / 4, 256, 0, stream>>>(rs, srcs, X1b, X2, agg);
        k_gru<<<N_LINKS / 256, 256, 0, stream>>>(agg, h, W_ih, W_hh, b_ih, b_hh,
                                                 W_msg, b_msg, state, X1b, X2,
                                                 feature, flags);
    }
    k_readout<<<1, 64, 0, stream>>>(feature, W_r1, b_r1, W_r2, b_r2, W_out, b_out, out);
}